// Round 1
// baseline (290.939 us; speedup 1.0000x reference)
//
#include <hip/hip_runtime.h>
#include <hip/hip_bf16.h>

typedef unsigned short u16;
typedef __attribute__((ext_vector_type(8))) __bf16 bf16x8;
typedef __attribute__((ext_vector_type(4))) float f32x4;

#define B_ 4
#define C_ 64
#define HW_ 4096

__device__ __forceinline__ u16 f2bf(float f) {
    unsigned u = __builtin_bit_cast(unsigned, f);
    u += 0x7FFFu + ((u >> 16) & 1u);
    return (u16)(u >> 16);
}

// ---------------------------------------------------------------- QKV ------
__global__ __launch_bounds__(256) void qkv_kernel(
    const float* __restrict__ x,
    const float* __restrict__ Wq, const float* __restrict__ bq,
    const float* __restrict__ Wk, const float* __restrict__ bk,
    const float* __restrict__ Wv, const float* __restrict__ bv,
    u16* __restrict__ Qt, u16* __restrict__ Kt, u16* __restrict__ Vm)
{
    __shared__ float xs[64][65];
    __shared__ float wsm[64][64];
    const int t = threadIdx.x;
    const int b = blockIdx.x >> 6;
    const int n0 = (blockIdx.x & 63) << 6;

    for (int i = 0; i < 16; ++i) {
        int lin = t + i * 256;
        int c = lin >> 6, nn = lin & 63;
        xs[c][nn] = x[(size_t)(b * 64 + c) * 4096 + n0 + nn];
    }
    const int n = t & 63, g = t >> 6;
    const float* Wmat[3] = {Wq, Wk, Wv};
    const float* bias[3] = {bq, bk, bv};
#pragma unroll
    for (int m = 0; m < 3; ++m) {
        __syncthreads();                       // xs ready / wsm free
        for (int i = 0; i < 16; ++i) {
            int lin = t + i * 256;
            wsm[lin >> 6][lin & 63] = Wmat[m][lin];
        }
        __syncthreads();
        float acc[16];
#pragma unroll
        for (int oc = 0; oc < 16; ++oc) acc[oc] = bias[m][g * 16 + oc];
        for (int c0 = 0; c0 < 64; c0 += 4) {
            float x0 = xs[c0][n], x1 = xs[c0 + 1][n], x2 = xs[c0 + 2][n], x3 = xs[c0 + 3][n];
#pragma unroll
            for (int oc = 0; oc < 16; ++oc) {
                const float4 w4 = *reinterpret_cast<const float4*>(&wsm[g * 16 + oc][c0]);
                acc[oc] += w4.x * x0 + w4.y * x1 + w4.z * x2 + w4.w * x3;
            }
        }
        if (m < 2) {
            u16 tmp[16];
#pragma unroll
            for (int oc = 0; oc < 16; ++oc) tmp[oc] = f2bf(acc[oc]);
            u16* dst = (m == 0 ? Qt : Kt) + ((size_t)(b * 4096 + n0 + n)) * 64 + g * 16;
            *reinterpret_cast<uint4*>(dst)     = *reinterpret_cast<const uint4*>(&tmp[0]);
            *reinterpret_cast<uint4*>(dst + 8) = *reinterpret_cast<const uint4*>(&tmp[8]);
        } else {
            __syncthreads();                   // all xs reads done
#pragma unroll
            for (int oc = 0; oc < 16; ++oc) xs[g * 16 + oc][n] = acc[oc];
            __syncthreads();
            const int c = t >> 2, chk = t & 3;
            u16 tmp[16];
#pragma unroll
            for (int j = 0; j < 16; ++j) tmp[j] = f2bf(xs[c][chk * 16 + j]);
            u16* dst = Vm + (size_t)(b * 64 + c) * 4096 + n0 + chk * 16;
            *reinterpret_cast<uint4*>(dst)     = *reinterpret_cast<const uint4*>(&tmp[0]);
            *reinterpret_cast<uint4*>(dst + 8) = *reinterpret_cast<const uint4*>(&tmp[8]);
        }
    }
}

// ---------------------------------------------------------------- edge -----
__global__ __launch_bounds__(256) void edge_kernel(
    const float* __restrict__ x,
    const float* __restrict__ We1, const float* __restrict__ be1,
    const float* __restrict__ bn_w, const float* __restrict__ bn_b,
    const float* __restrict__ bn_mean, const float* __restrict__ bn_var,
    const float* __restrict__ We2, const float* __restrict__ be2,
    const float* __restrict__ beta, float* __restrict__ wkey)
{
    __shared__ float xr[3][16][66];     // zero-padded cols [0] and [65]
    __shared__ float wl[32][145];       // chunk of We1, [ch][cil*9+kh*3+kw]
    __shared__ float red[32][65];
    const int t = threadIdx.x;
    const int b = blockIdx.x >> 6, h = blockIdx.x & 63;
    const int ch = t >> 3, pg = t & 7;  // ch 0..31, 8 pixels per thread

    float acc[8];
#pragma unroll
    for (int j = 0; j < 8; ++j) acc[j] = 0.f;

    for (int ck = 0; ck < 4; ++ck) {
        __syncthreads();
        // weights chunk: 16 ci x 9 x 32 ch = 4608 floats
        for (int i = 0; i < 18; ++i) {
            int lin = t + i * 256;
            int c2 = lin / 144; int idx = lin - c2 * 144;
            wl[c2][idx] = We1[c2 * 576 + ck * 144 + idx];
        }
        // x rows: 3 x 16 x 64 = 3072 floats
        for (int i = 0; i < 12; ++i) {
            int lin = t + i * 256;
            int kh = lin >> 10; int cil = (lin >> 6) & 15; int w = lin & 63;
            int hs = h + kh - 1;
            float v = 0.f;
            if (hs >= 0 && hs < 64)
                v = x[((size_t)(b * 64 + ck * 16 + cil) * 64 + hs) * 64 + w];
            xr[kh][cil][w + 1] = v;
        }
        if (t < 48) { int kh = t / 16, cil = t & 15; xr[kh][cil][0] = 0.f; xr[kh][cil][65] = 0.f; }
        __syncthreads();
        for (int cil = 0; cil < 16; ++cil) {
#pragma unroll
            for (int kh = 0; kh < 3; ++kh) {
                float r[10];
#pragma unroll
                for (int j = 0; j < 10; ++j) r[j] = xr[kh][cil][pg * 8 + j];
                const float* wp = &wl[ch][(cil * 3 + kh) * 3];
                float w0 = wp[0], w1 = wp[1], w2 = wp[2];
#pragma unroll
                for (int j = 0; j < 8; ++j) acc[j] += w0 * r[j] + w1 * r[j + 1] + w2 * r[j + 2];
            }
        }
    }
    // BN (folded) + ReLU + 1x1 partial
    float scale = bn_w[ch] * rsqrtf(bn_var[ch] + 1e-5f);
    float shift = (be1[ch] - bn_mean[ch]) * scale + bn_b[ch];
    float w2 = We2[ch];
#pragma unroll
    for (int j = 0; j < 8; ++j) {
        float hv = fmaxf(acc[j] * scale + shift, 0.f);
        red[ch][pg * 8 + j] = w2 * hv;
    }
    __syncthreads();
    if (t < 64) {
        float s = be2[0];
#pragma unroll
        for (int c2 = 0; c2 < 32; ++c2) s += red[c2][t];
        float sg = 1.f / (1.f + __expf(-s));
        wkey[(size_t)b * 4096 + h * 64 + t] = 1.f + beta[0] * sg;
    }
}

// ------------------------------------------------------------- attention ---
__global__ __launch_bounds__(256) void attn_kernel(
    const u16* __restrict__ Qt, const u16* __restrict__ Kt,
    const u16* __restrict__ Vm, const float* __restrict__ wkey,
    const float* __restrict__ x, const float* __restrict__ g_gamma,
    float* __restrict__ out)
{
    // 4 bf16 tiles (64 x 72-stride) + 64-float w buffer
    __shared__ __align__(16) u16 smem[4 * 4608 + 128];
    u16* q_s = smem;
    u16* k_s = smem + 4608;
    u16* v_s = smem + 2 * 4608;
    u16* p_s = smem + 3 * 4608;
    float* w_s = (float*)(smem + 4 * 4608);
    float* o_t = (float*)smem;   // epilogue overlay: 64*72 floats = q_s+k_s region

    const int t = threadIdx.x;
    const int b = blockIdx.x >> 6;
    const int n0q = (blockIdx.x & 63) << 6;
    const int lane = t & 63, wv = t >> 6;
    const int quad = lane >> 4, l15 = lane & 15;
    const int qb = wv * 16;

    // stage Q tile (once)
#pragma unroll
    for (int i = 0; i < 2; ++i) {
        int lin = t + i * 256;
        int row = lin >> 3, chk = lin & 7;
        const uint4 d = *reinterpret_cast<const uint4*>(
            Qt + ((size_t)(b * 4096 + n0q + row) * 64 + chk * 8));
        *reinterpret_cast<uint4*>(&q_s[row * 72 + chk * 8]) = d;
    }

    uint4 kreg[2], vreg[2];
    float wreg = 0.f;
    auto load_tiles = [&](int kt) {
#pragma unroll
        for (int i = 0; i < 2; ++i) {
            int row = (t >> 3) + 32 * i, chk = t & 7;
            kreg[i] = *reinterpret_cast<const uint4*>(
                Kt + ((size_t)(b * 4096 + kt * 64 + row) * 64 + chk * 8));
            vreg[i] = *reinterpret_cast<const uint4*>(
                Vm + ((size_t)(b * 64 + row) * 4096 + kt * 64 + chk * 8));
        }
        if (t < 64) wreg = wkey[(size_t)b * 4096 + kt * 64 + t];
    };
    load_tiles(0);

    __syncthreads();   // Q staged
    bf16x8 aq0 = *reinterpret_cast<const bf16x8*>(&q_s[(qb + l15) * 72 + quad * 8]);
    bf16x8 aq1 = *reinterpret_cast<const bf16x8*>(&q_s[(qb + l15) * 72 + 32 + quad * 8]);

    f32x4 o[4];
    float m_i[4], l_i[4];
#pragma unroll
    for (int f = 0; f < 4; ++f) o[f] = (f32x4){0.f, 0.f, 0.f, 0.f};
#pragma unroll
    for (int r = 0; r < 4; ++r) { m_i[r] = -INFINITY; l_i[r] = 0.f; }
    const float gamma = g_gamma[0];

    for (int kt = 0; kt < 64; ++kt) {
        __syncthreads();   // previous tile's LDS reads done
#pragma unroll
        for (int i = 0; i < 2; ++i) {
            int row = (t >> 3) + 32 * i, chk = t & 7;
            *reinterpret_cast<uint4*>(&k_s[row * 72 + chk * 8]) = kreg[i];
            *reinterpret_cast<uint4*>(&v_s[row * 72 + chk * 8]) = vreg[i];
        }
        if (t < 64) w_s[t] = wreg;
        if (kt + 1 < 64) load_tiles(kt + 1);   // prefetch overlaps compute
        __syncthreads();

        // S = Q x K^T   (rows: 16 queries of this wave, cols: 64 keys)
        f32x4 s[4];
#pragma unroll
        for (int f = 0; f < 4; ++f) {
            bf16x8 b0 = *reinterpret_cast<const bf16x8*>(&k_s[(f * 16 + l15) * 72 + quad * 8]);
            bf16x8 b1 = *reinterpret_cast<const bf16x8*>(&k_s[(f * 16 + l15) * 72 + 32 + quad * 8]);
            f32x4 acc = (f32x4){0.f, 0.f, 0.f, 0.f};
            acc = __builtin_amdgcn_mfma_f32_16x16x32_bf16(aq0, b0, acc, 0, 0, 0);
            acc = __builtin_amdgcn_mfma_f32_16x16x32_bf16(aq1, b1, acc, 0, 0, 0);
            s[f] = acc;
        }
        float wv4[4];
#pragma unroll
        for (int f = 0; f < 4; ++f) wv4[f] = w_s[f * 16 + l15];

        // online softmax (+ key weight), rows quad*4+r, 16-lane butterflies
#pragma unroll
        for (int r = 0; r < 4; ++r) {
            float smax = fmaxf(fmaxf(s[0][r], s[1][r]), fmaxf(s[2][r], s[3][r]));
            smax = fmaxf(smax, __shfl_xor(smax, 1));
            smax = fmaxf(smax, __shfl_xor(smax, 2));
            smax = fmaxf(smax, __shfl_xor(smax, 4));
            smax = fmaxf(smax, __shfl_xor(smax, 8));
            float mnew = fmaxf(m_i[r], smax);
            float alpha = __expf(m_i[r] - mnew);
            m_i[r] = mnew;
            float p0 = __expf(s[0][r] - mnew) * wv4[0];
            float p1 = __expf(s[1][r] - mnew) * wv4[1];
            float p2 = __expf(s[2][r] - mnew) * wv4[2];
            float p3 = __expf(s[3][r] - mnew) * wv4[3];
            float psum = (p0 + p1) + (p2 + p3);
            psum += __shfl_xor(psum, 1);
            psum += __shfl_xor(psum, 2);
            psum += __shfl_xor(psum, 4);
            psum += __shfl_xor(psum, 8);
            l_i[r] = alpha * l_i[r] + psum;
#pragma unroll
            for (int f = 0; f < 4; ++f) o[f][r] = o[f][r] * alpha;
            const int prow = (qb + quad * 4 + r) * 72 + l15;
            p_s[prow]      = f2bf(p0);
            p_s[prow + 16] = f2bf(p1);
            p_s[prow + 32] = f2bf(p2);
            p_s[prow + 48] = f2bf(p3);
        }
        __syncthreads();   // P visible (safety)

        // O += P x V^T
        bf16x8 ap0 = *reinterpret_cast<const bf16x8*>(&p_s[(qb + l15) * 72 + quad * 8]);
        bf16x8 ap1 = *reinterpret_cast<const bf16x8*>(&p_s[(qb + l15) * 72 + 32 + quad * 8]);
#pragma unroll
        for (int f = 0; f < 4; ++f) {
            bf16x8 b0 = *reinterpret_cast<const bf16x8*>(&v_s[(f * 16 + l15) * 72 + quad * 8]);
            bf16x8 b1 = *reinterpret_cast<const bf16x8*>(&v_s[(f * 16 + l15) * 72 + 32 + quad * 8]);
            o[f] = __builtin_amdgcn_mfma_f32_16x16x32_bf16(ap0, b0, o[f], 0, 0, 0);
            o[f] = __builtin_amdgcn_mfma_f32_16x16x32_bf16(ap1, b1, o[f], 0, 0, 0);
        }
    }

    // epilogue: divide by l, scale by gamma, transpose through LDS, add residual
    __syncthreads();
    float inv[4];
#pragma unroll
    for (int r = 0; r < 4; ++r) inv[r] = gamma / fmaxf(l_i[r], 1e-12f);
#pragma unroll
    for (int f = 0; f < 4; ++f)
#pragma unroll
        for (int r = 0; r < 4; ++r)
            o_t[(f * 16 + l15) * 72 + qb + quad * 4 + r] = o[f][r] * inv[r];
    __syncthreads();
    {
        const int c = t >> 2, chk = t & 3;
        const size_t gidx = (size_t)(b * 64 + c) * 4096 + n0q + chk * 16;
#pragma unroll
        for (int j = 0; j < 4; ++j) {
            float4 xv = *reinterpret_cast<const float4*>(&x[gidx + j * 4]);
            float4 ov = *reinterpret_cast<const float4*>(&o_t[c * 72 + chk * 16 + j * 4]);
            float4 r4;
            r4.x = ov.x + xv.x; r4.y = ov.y + xv.y; r4.z = ov.z + xv.z; r4.w = ov.w + xv.w;
            *reinterpret_cast<float4*>(&out[gidx + j * 4]) = r4;
        }
    }
}

// ---------------------------------------------------------------- launch ---
extern "C" void kernel_launch(void* const* d_in, const int* in_sizes, int n_in,
                              void* d_out, int out_size, void* d_ws, size_t ws_size,
                              hipStream_t stream) {
    const float* x      = (const float*)d_in[0];
    const float* Wq     = (const float*)d_in[1];
    const float* bq     = (const float*)d_in[2];
    const float* Wk     = (const float*)d_in[3];
    const float* bk     = (const float*)d_in[4];
    const float* Wv     = (const float*)d_in[5];
    const float* bv     = (const float*)d_in[6];
    const float* We1    = (const float*)d_in[7];
    const float* be1    = (const float*)d_in[8];
    const float* bn_w   = (const float*)d_in[9];
    const float* bn_b   = (const float*)d_in[10];
    const float* bn_mean= (const float*)d_in[11];
    const float* bn_var = (const float*)d_in[12];
    const float* We2    = (const float*)d_in[13];
    const float* be2    = (const float*)d_in[14];
    const float* gamma  = (const float*)d_in[15];
    const float* beta   = (const float*)d_in[16];

    char* ws = (char*)d_ws;
    u16*   Qt   = (u16*)ws;                                  // 2 MB
    u16*   Kt   = (u16*)(ws + (size_t)2 * 1024 * 1024);      // 2 MB
    u16*   Vm   = (u16*)(ws + (size_t)4 * 1024 * 1024);      // 2 MB
    float* wkey = (float*)(ws + (size_t)6 * 1024 * 1024);    // 64 KB

    float* out = (float*)d_out;

    qkv_kernel<<<dim3(256), dim3(256), 0, stream>>>(x, Wq, bq, Wk, bk, Wv, bv, Qt, Kt, Vm);
    edge_kernel<<<dim3(256), dim3(256), 0, stream>>>(x, We1, be1, bn_w, bn_b, bn_mean, bn_var,
                                                     We2, be2, beta, wkey);
    attn_kernel<<<dim3(256), dim3(256), 0, stream>>>(Qt, Kt, Vm, wkey, x, gamma, out);
}

// Round 2
// 197.227 us; speedup vs baseline: 1.4752x; 1.4752x over previous
//
#include <hip/hip_runtime.h>
#include <hip/hip_bf16.h>

typedef unsigned short u16;
typedef __attribute__((ext_vector_type(8))) __bf16 bf16x8;
typedef __attribute__((ext_vector_type(4))) float f32x4;

__device__ __forceinline__ u16 f2bf(float f) {
    unsigned u = __builtin_bit_cast(unsigned, f);
    u += 0x7FFFu + ((u >> 16) & 1u);
    return (u16)(u >> 16);
}
__device__ __forceinline__ float bf2f(u16 v) {
    unsigned u = ((unsigned)v) << 16;
    return __builtin_bit_cast(float, u);
}

// ---------------------------------------------------------------- QKV ------
// grid 768: m = bid/256 (0=Q,1=K,2=V); per block one 64x64 n-tile of one matrix
__global__ __launch_bounds__(256) void qkv_kernel(
    const float* __restrict__ x,
    const float* __restrict__ Wq, const float* __restrict__ bq,
    const float* __restrict__ Wk, const float* __restrict__ bk,
    const float* __restrict__ Wv, const float* __restrict__ bv,
    u16* __restrict__ Qt, u16* __restrict__ Kt, u16* __restrict__ Vm)
{
    __shared__ float xs[64][65];
    __shared__ float wsm[64][64];
    const int t = threadIdx.x;
    const int m = blockIdx.x >> 8;            // 0..2
    const int r8 = blockIdx.x & 255;
    const int b = r8 >> 6;
    const int n0 = (r8 & 63) << 6;

    const float* W  = (m == 0) ? Wq : (m == 1) ? Wk : Wv;
    const float* bi = (m == 0) ? bq : (m == 1) ? bk : bv;

    for (int i = 0; i < 16; ++i) {
        int lin = t + i * 256;
        xs[lin >> 6][lin & 63] = x[(size_t)(b * 64 + (lin >> 6)) * 4096 + n0 + (lin & 63)];
        wsm[lin >> 6][lin & 63] = W[lin];
    }
    __syncthreads();

    const int n = t & 63, g = t >> 6;
    float acc[16];
#pragma unroll
    for (int oc = 0; oc < 16; ++oc) acc[oc] = bi[g * 16 + oc];
    for (int c0 = 0; c0 < 64; c0 += 4) {
        float x0 = xs[c0][n], x1 = xs[c0 + 1][n], x2 = xs[c0 + 2][n], x3 = xs[c0 + 3][n];
#pragma unroll
        for (int oc = 0; oc < 16; ++oc) {
            const float4 w4 = *reinterpret_cast<const float4*>(&wsm[g * 16 + oc][c0]);
            acc[oc] += w4.x * x0 + w4.y * x1 + w4.z * x2 + w4.w * x3;
        }
    }
    if (m < 2) {
        u16 tmp[16];
#pragma unroll
        for (int oc = 0; oc < 16; ++oc) tmp[oc] = f2bf(acc[oc]);
        u16* dst = (m == 0 ? Qt : Kt) + ((size_t)(b * 4096 + n0 + n)) * 64 + g * 16;
        *reinterpret_cast<uint4*>(dst)     = *reinterpret_cast<const uint4*>(&tmp[0]);
        *reinterpret_cast<uint4*>(dst + 8) = *reinterpret_cast<const uint4*>(&tmp[8]);
    } else {
        __syncthreads();
#pragma unroll
        for (int oc = 0; oc < 16; ++oc) xs[g * 16 + oc][n] = acc[oc];
        __syncthreads();
        const int c = t >> 2, chk = t & 3;
        u16 tmp[16];
#pragma unroll
        for (int j = 0; j < 16; ++j) tmp[j] = f2bf(xs[c][chk * 16 + j]);
        u16* dst = Vm + (size_t)(b * 64 + c) * 4096 + n0 + chk * 16;
        *reinterpret_cast<uint4*>(dst)     = *reinterpret_cast<const uint4*>(&tmp[0]);
        *reinterpret_cast<uint4*>(dst + 8) = *reinterpret_cast<const uint4*>(&tmp[8]);
    }
}

// ---------------------------------------------------------------- edge -----
// grid 512: (b,h) x w-half; each block computes 32 output pixels of one row
__global__ __launch_bounds__(256) void edge_kernel(
    const float* __restrict__ x,
    const float* __restrict__ We1, const float* __restrict__ be1,
    const float* __restrict__ bn_w, const float* __restrict__ bn_b,
    const float* __restrict__ bn_mean, const float* __restrict__ bn_var,
    const float* __restrict__ We2, const float* __restrict__ be2,
    const float* __restrict__ beta, float* __restrict__ wkey)
{
    __shared__ float xr[3][16][36];     // cols j<->global w0-1+j, j in [0,34)
    __shared__ float wl[32][145];
    __shared__ float red[32][33];
    const int t = threadIdx.x;
    const int w0 = (blockIdx.x & 1) << 5;
    const int bh = blockIdx.x >> 1;
    const int b = bh >> 6, h = bh & 63;
    const int ch = t >> 3, pg = t & 7, px = pg * 4;

    float acc[4] = {0.f, 0.f, 0.f, 0.f};

    for (int ck = 0; ck < 4; ++ck) {
        __syncthreads();
        for (int i = 0; i < 18; ++i) {
            int lin = t + i * 256;
            int c2 = lin / 144; int idx = lin - c2 * 144;
            wl[c2][idx] = We1[c2 * 576 + ck * 144 + idx];
        }
        for (int i = 0; i < 7; ++i) {
            int lin = t + i * 256;
            if (lin < 1728) {
                int kh = lin / 576; int rem = lin - kh * 576;
                int cil = rem / 36; int j = rem - cil * 36;
                int hs = h + kh - 1;
                int wg = w0 - 1 + j;
                float v = 0.f;
                if (hs >= 0 && hs < 64 && wg >= 0 && wg < 64 && j < 34)
                    v = x[((size_t)(b * 64 + ck * 16 + cil) * 64 + hs) * 64 + wg];
                xr[kh][cil][j] = v;
            }
        }
        __syncthreads();
        for (int cil = 0; cil < 16; ++cil) {
#pragma unroll
            for (int kh = 0; kh < 3; ++kh) {
                float r[6];
#pragma unroll
                for (int j = 0; j < 6; ++j) r[j] = xr[kh][cil][px + j];
                const float* wp = &wl[ch][(cil * 3 + kh) * 3];
                float w0c = wp[0], w1c = wp[1], w2c = wp[2];
#pragma unroll
                for (int j = 0; j < 4; ++j) acc[j] += w0c * r[j] + w1c * r[j + 1] + w2c * r[j + 2];
            }
        }
    }
    float scale = bn_w[ch] * rsqrtf(bn_var[ch] + 1e-5f);
    float shift = (be1[ch] - bn_mean[ch]) * scale + bn_b[ch];
    float w2 = We2[ch];
#pragma unroll
    for (int j = 0; j < 4; ++j) {
        float hv = fmaxf(acc[j] * scale + shift, 0.f);
        red[ch][px + j] = w2 * hv;
    }
    __syncthreads();
    if (t < 32) {
        float s = be2[0];
#pragma unroll
        for (int c2 = 0; c2 < 32; ++c2) s += red[c2][t];
        float sg = 1.f / (1.f + __expf(-s));
        wkey[(size_t)b * 4096 + h * 64 + w0 + t] = 1.f + beta[0] * sg;
    }
}

// ------------------------------------------------------------- attention ---
// grid 512 = 128 q-blocks (128 rows) x 4 k-splits. 256 thr = 4 waves x 32 q rows.
// S^T = K*Q^T via MFMA (A=K, B=Q, both direct from global); fixed-offset
// softmax exp(s-12)*w; P transposed through wave-local LDS; O += P*V^T
// (V direct from global). No __syncthreads in the k-loop.
__global__ __launch_bounds__(256, 2) void attn_kernel(
    const u16* __restrict__ Qt, const u16* __restrict__ Kt,
    const u16* __restrict__ Vm, const float* __restrict__ wkey,
    u16* __restrict__ O_part, float* __restrict__ l_part)
{
    __shared__ __align__(16) u16 p_s_all[4 * 32 * 68];
    const int t = threadIdx.x;
    const int qi = blockIdx.x >> 2;        // 0..127
    const int split = blockIdx.x & 3;
    const int b = qi >> 5;
    const int n0 = (qi & 31) << 7;         // 128 q rows per block
    const int wv = t >> 6, lane = t & 63;
    const int quad = lane >> 4, l15 = lane & 15;
    u16* p_s = p_s_all + wv * (32 * 68);

    const u16* Qb = Qt + (size_t)b * 4096 * 64;
    const u16* Kb = Kt + (size_t)b * 4096 * 64;
    const u16* Vb = Vm + (size_t)b * 64 * 4096;
    const float* wb = wkey + (size_t)b * 4096;

    // Q fragments: register-resident for the whole kernel
    bf16x8 qf[2][2];
#pragma unroll
    for (int nt = 0; nt < 2; ++nt)
#pragma unroll
        for (int h = 0; h < 2; ++h)
            qf[nt][h] = __builtin_bit_cast(bf16x8, *reinterpret_cast<const uint4*>(
                Qb + (size_t)(n0 + wv * 32 + nt * 16 + l15) * 64 + h * 32 + quad * 8));

    const int kt0 = split * 16;
    uint4 kf[4][2];
    float4 wf[4];
#pragma unroll
    for (int mt = 0; mt < 4; ++mt) {
#pragma unroll
        for (int h = 0; h < 2; ++h)
            kf[mt][h] = *reinterpret_cast<const uint4*>(
                Kb + (size_t)(kt0 * 64 + mt * 16 + l15) * 64 + h * 32 + quad * 8);
        wf[mt] = *reinterpret_cast<const float4*>(wb + kt0 * 64 + mt * 16 + quad * 4);
    }

    f32x4 o[2][4];
#pragma unroll
    for (int m2 = 0; m2 < 2; ++m2)
#pragma unroll
        for (int f = 0; f < 4; ++f) o[m2][f] = (f32x4){0.f, 0.f, 0.f, 0.f};
    float l_acc[2] = {0.f, 0.f};

    for (int kt = kt0; kt < kt0 + 16; ++kt) {
        // V fragments for THIS tile (consumed after softmax -> latency covered)
        uint4 vf[4][2];
#pragma unroll
        for (int f = 0; f < 4; ++f)
#pragma unroll
            for (int h = 0; h < 2; ++h)
                vf[f][h] = *reinterpret_cast<const uint4*>(
                    Vb + (size_t)(f * 16 + l15) * 4096 + kt * 64 + h * 32 + quad * 8);

        // S^T tile: rows=keys (mt), cols=q (nt)
        f32x4 s[4][2];
#pragma unroll
        for (int mt = 0; mt < 4; ++mt)
#pragma unroll
            for (int nt = 0; nt < 2; ++nt) {
                f32x4 a = (f32x4){0.f, 0.f, 0.f, 0.f};
                a = __builtin_amdgcn_mfma_f32_16x16x32_bf16(
                        __builtin_bit_cast(bf16x8, kf[mt][0]), qf[nt][0], a, 0, 0, 0);
                a = __builtin_amdgcn_mfma_f32_16x16x32_bf16(
                        __builtin_bit_cast(bf16x8, kf[mt][1]), qf[nt][1], a, 0, 0, 0);
                s[mt][nt] = a;
            }

        const int ktn = (kt + 1 < kt0 + 16) ? kt + 1 : kt0;
        // K fragments for next tile (kf just consumed)
#pragma unroll
        for (int mt = 0; mt < 4; ++mt)
#pragma unroll
            for (int h = 0; h < 2; ++h)
                kf[mt][h] = *reinterpret_cast<const uint4*>(
                    Kb + (size_t)(ktn * 64 + mt * 16 + l15) * 64 + h * 32 + quad * 8);

        // softmax (fixed offset) + packed P write (4 consecutive keys per lane)
#pragma unroll
        for (int mt = 0; mt < 4; ++mt)
#pragma unroll
            for (int nt = 0; nt < 2; ++nt) {
                u16 pk[4];
#pragma unroll
                for (int r = 0; r < 4; ++r) {
                    float p = __expf(s[mt][nt][r] - 12.0f) *
                              reinterpret_cast<const float*>(&wf[mt])[r];
                    l_acc[nt] += p;
                    pk[r] = f2bf(p);
                }
                uint2 packed;
                packed.x = (unsigned)pk[0] | ((unsigned)pk[1] << 16);
                packed.y = (unsigned)pk[2] | ((unsigned)pk[3] << 16);
                *reinterpret_cast<uint2*>(
                    &p_s[(nt * 16 + l15) * 68 + mt * 16 + quad * 4]) = packed;
            }

        // w for next tile (wf just consumed)
#pragma unroll
        for (int mt = 0; mt < 4; ++mt)
            wf[mt] = *reinterpret_cast<const float4*>(wb + ktn * 64 + mt * 16 + quad * 4);

        // P A-fragments (wave-local LDS round-trip)
        bf16x8 pa[2][2];
#pragma unroll
        for (int m2 = 0; m2 < 2; ++m2)
#pragma unroll
            for (int h = 0; h < 2; ++h) {
                uint2 lo = *reinterpret_cast<const uint2*>(
                    &p_s[(m2 * 16 + l15) * 68 + h * 32 + quad * 8]);
                uint2 hi = *reinterpret_cast<const uint2*>(
                    &p_s[(m2 * 16 + l15) * 68 + h * 32 + quad * 8 + 4]);
                uint4 c4; c4.x = lo.x; c4.y = lo.y; c4.z = hi.x; c4.w = hi.y;
                pa[m2][h] = __builtin_bit_cast(bf16x8, c4);
            }

        // O += P * V^T
#pragma unroll
        for (int m2 = 0; m2 < 2; ++m2)
#pragma unroll
            for (int f = 0; f < 4; ++f) {
                o[m2][f] = __builtin_amdgcn_mfma_f32_16x16x32_bf16(
                    pa[m2][0], __builtin_bit_cast(bf16x8, vf[f][0]), o[m2][f], 0, 0, 0);
                o[m2][f] = __builtin_amdgcn_mfma_f32_16x16x32_bf16(
                    pa[m2][1], __builtin_bit_cast(bf16x8, vf[f][1]), o[m2][f], 0, 0, 0);
            }
    }

    // epilogue: l reduce over quads, write partials
    const size_t pbase = ((size_t)qi * 4 + split) * 128;
    float lred[2];
#pragma unroll
    for (int nt = 0; nt < 2; ++nt) {
        float v = l_acc[nt];
        v += __shfl_xor(v, 16);
        v += __shfl_xor(v, 32);
        lred[nt] = v;
    }
    if (lane < 16) {
#pragma unroll
        for (int nt = 0; nt < 2; ++nt)
            l_part[pbase + wv * 32 + nt * 16 + lane] = lred[nt];
    }
#pragma unroll
    for (int m2 = 0; m2 < 2; ++m2)
#pragma unroll
        for (int f = 0; f < 4; ++f)
#pragma unroll
            for (int r = 0; r < 4; ++r)
                O_part[(pbase + wv * 32 + m2 * 16 + quad * 4 + r) * 64 + f * 16 + l15] =
                    f2bf(o[m2][f][r]);
}

// ---------------------------------------------------------------- combine --
// grid 256: sum 4 split-partials, normalize by l, gamma*out + x (transposed)
__global__ __launch_bounds__(256) void combine_kernel(
    const u16* __restrict__ O_part, const float* __restrict__ l_part,
    const float* __restrict__ x, const float* __restrict__ g_gamma,
    float* __restrict__ out)
{
    __shared__ float ot[64 * 67];
    __shared__ float ls[64];
    const int t = threadIdx.x;
    const int b = blockIdx.x >> 6;
    const int n0c = (blockIdx.x & 63) << 6;
    const int qi = (b << 5) + (n0c >> 7);
    const int row0 = n0c & 127;
    const float gamma = g_gamma[0];

    const int r = t >> 2, seg = t & 3;
    float acc[16];
#pragma unroll
    for (int i = 0; i < 16; ++i) acc[i] = 0.f;
#pragma unroll
    for (int s4 = 0; s4 < 4; ++s4) {
        const u16* p = O_part + ((((size_t)qi * 4 + s4) * 128) + row0 + r) * 64 + seg * 16;
        uint4 u0 = *reinterpret_cast<const uint4*>(p);
        uint4 u1 = *reinterpret_cast<const uint4*>(p + 8);
        const unsigned* uu0 = reinterpret_cast<const unsigned*>(&u0);
        const unsigned* uu1 = reinterpret_cast<const unsigned*>(&u1);
#pragma unroll
        for (int i = 0; i < 4; ++i) {
            acc[2 * i]     += bf2f((u16)(uu0[i] & 0xFFFF));
            acc[2 * i + 1] += bf2f((u16)(uu0[i] >> 16));
            acc[8 + 2 * i]     += bf2f((u16)(uu1[i] & 0xFFFF));
            acc[8 + 2 * i + 1] += bf2f((u16)(uu1[i] >> 16));
        }
    }
#pragma unroll
    for (int i = 0; i < 16; ++i) ot[r * 67 + seg * 16 + i] = acc[i];
    if (seg == 0) {
        float lsum = 0.f;
#pragma unroll
        for (int s4 = 0; s4 < 4; ++s4)
            lsum += l_part[(((size_t)qi * 4 + s4) * 128) + row0 + r];
        ls[r] = gamma / fmaxf(lsum, 1e-30f);
    }
    __syncthreads();
    const int c = t >> 2, chk = t & 3;
    const size_t gbase = ((size_t)(b * 64 + c)) * 4096 + n0c + chk * 16;
#pragma unroll
    for (int j = 0; j < 4; ++j) {
        float4 xv = *reinterpret_cast<const float4*>(&x[gbase + j * 4]);
        float4 rv;
        int nl = chk * 16 + j * 4;
        rv.x = ot[(nl + 0) * 67 + c] * ls[nl + 0] + xv.x;
        rv.y = ot[(nl + 1) * 67 + c] * ls[nl + 1] + xv.y;
        rv.z = ot[(nl + 2) * 67 + c] * ls[nl + 2] + xv.z;
        rv.w = ot[(nl + 3) * 67 + c] * ls[nl + 3] + xv.w;
        *reinterpret_cast<float4*>(&out[gbase + j * 4]) = rv;
    }
}

// ---------------------------------------------------------------- launch ---
extern "C" void kernel_launch(void* const* d_in, const int* in_sizes, int n_in,
                              void* d_out, int out_size, void* d_ws, size_t ws_size,
                              hipStream_t stream) {
    const float* x      = (const float*)d_in[0];
    const float* Wq     = (const float*)d_in[1];
    const float* bq     = (const float*)d_in[2];
    const float* Wk     = (const float*)d_in[3];
    const float* bk     = (const float*)d_in[4];
    const float* Wv     = (const float*)d_in[5];
    const float* bv     = (const float*)d_in[6];
    const float* We1    = (const float*)d_in[7];
    const float* be1    = (const float*)d_in[8];
    const float* bn_w   = (const float*)d_in[9];
    const float* bn_b   = (const float*)d_in[10];
    const float* bn_mean= (const float*)d_in[11];
    const float* bn_var = (const float*)d_in[12];
    const float* We2    = (const float*)d_in[13];
    const float* be2    = (const float*)d_in[14];
    const float* gamma  = (const float*)d_in[15];
    const float* beta   = (const float*)d_in[16];

    char* ws = (char*)d_ws;
    const size_t MB = 1024 * 1024;
    u16*   Qt     = (u16*)ws;                       // 2 MB
    u16*   Kt     = (u16*)(ws + 2 * MB);            // 2 MB
    u16*   Vm     = (u16*)(ws + 4 * MB);            // 2 MB
    float* wkey   = (float*)(ws + 6 * MB);          // 64 KB
    u16*   O_part = (u16*)(ws + 7 * MB);            // 512*128*64*2 = 8.39 MB
    float* l_part = (float*)(ws + 16 * MB);         // 512*128*4 = 256 KB

    float* out = (float*)d_out;

    qkv_kernel<<<dim3(768), dim3(256), 0, stream>>>(x, Wq, bq, Wk, bk, Wv, bv, Qt, Kt, Vm);
    edge_kernel<<<dim3(512), dim3(256), 0, stream>>>(x, We1, be1, bn_w, bn_b, bn_mean, bn_var,
                                                     We2, be2, beta, wkey);
    attn_kernel<<<dim3(512), dim3(256), 0, stream>>>(Qt, Kt, Vm, wkey, O_part, l_part);
    combine_kernel<<<dim3(256), dim3(256), 0, stream>>>(O_part, l_part, x, gamma, out);
}